// Round 6
// baseline (65.133 us; speedup 1.0000x reference)
//
#include <hip/hip_runtime.h>
#include <math.h>

#define NPT 320
#define DDIM 256
#define NN2 (NPT*NPT)          // 102400
#define MINN 1e-15f

#define CHUNKS 8
#define PLANE4 (NN2/4)         // 25600 int4 per plane
#define CHUNK4 (PLANE4/CHUNKS) // 3200 int4 per chunk
#define TTHR   320             // threads per k_trip block (5 waves)
#define ITERS  (CHUNK4/TTHR)   // 10 int4 per thread
#define NBLK   (NPT*CHUNKS)    // 2560 blocks

// ---------------- fused: row stats + dm tile (no LDS staging) ----------------
__global__ __launch_bounds__(256) void k_pre(const float* __restrict__ off,
                                             const float* __restrict__ nrm,
                                             const float* __restrict__ curv,
                                             float* __restrict__ dm) {
    __shared__ float sx2i[16], sx2j[16], snnj[16], spaj[16];
    const float c = curv[0];
    const float sqrtc = sqrtf(c);
    const int I0 = blockIdx.y * 16, J0 = blockIdx.x * 16;
    const int t = threadIdx.x;
    const int r = t >> 4;
    const int cc = t & 15;

    // stats: thread (r,cc) sums 16-float slice cc of rows I0+r (off) and J0+r (off,nrm)
    {
        const float4* oi = (const float4*)&off[(I0 + r) * DDIM];
        const float4* oj = (const float4*)&off[(J0 + r) * DDIM];
        const float4* nj = (const float4*)&nrm[(J0 + r) * DDIM];
        float a0 = 0.f, a1 = 0.f, a2 = 0.f, a3 = 0.f;
#pragma unroll
        for (int q = 0; q < 4; ++q) {
            const float4 x = oi[cc * 4 + q];
            const float4 y = oj[cc * 4 + q];
            const float4 z = nj[cc * 4 + q];
            a0 = fmaf(x.x, x.x, fmaf(x.y, x.y, fmaf(x.z, x.z, fmaf(x.w, x.w, a0))));
            a1 = fmaf(y.x, y.x, fmaf(y.y, y.y, fmaf(y.z, y.z, fmaf(y.w, y.w, a1))));
            a2 = fmaf(z.x, z.x, fmaf(z.y, z.y, fmaf(z.z, z.z, fmaf(z.w, z.w, a2))));
            a3 = fmaf(y.x, z.x, fmaf(y.y, z.y, fmaf(y.z, z.z, fmaf(y.w, z.w, a3))));
        }
        for (int o = 1; o < 16; o <<= 1) {
            a0 += __shfl_xor(a0, o);
            a1 += __shfl_xor(a1, o);
            a2 += __shfl_xor(a2, o);
            a3 += __shfl_xor(a3, o);
        }
        if (cc == 0) { sx2i[r] = a0; sx2j[r] = a1; snnj[r] = a2; spaj[r] = a3; }
    }
    __syncthreads();

    // main: thread (ti,tj) computes dm[I0+ti][J0+tj]; rows served from L1/L2
    const int ti = r, tj = cc;
    const float4* rI = (const float4*)&off[(I0 + ti) * DDIM];
    const float4* rJ = (const float4*)&off[(J0 + tj) * DDIM];
    const float4* rN = (const float4*)&nrm[(J0 + tj) * DDIM];
    float g = 0.f, h = 0.f;
#pragma unroll 8
    for (int d4 = 0; d4 < DDIM / 4; ++d4) {
        const float4 ai = rI[d4];
        const float4 bj = rJ[d4];
        const float4 nj = rN[d4];
        g = fmaf(ai.x, bj.x, g); g = fmaf(ai.y, bj.y, g);
        g = fmaf(ai.z, bj.z, g); g = fmaf(ai.w, bj.w, g);
        h = fmaf(ai.x, nj.x, h); h = fmaf(ai.y, nj.y, h);
        h = fmaf(ai.z, nj.z, h); h = fmaf(ai.w, nj.w, h);
    }

    const float x2i = sx2i[ti], x2j = sx2j[tj], nnj = snnj[tj], paj = spaj[tj];
    const float cu = 1.f - 2.f * c * g + c * x2i;
    const float cv = 1.f - c * x2j;
    float den0 = 1.f - 2.f * c * g + c * c * x2i * x2j;
    den0 = fmaxf(den0, MINN);
    float dn2 = (cu * cu * x2j - 2.f * cu * cv * g + cv * cv * x2i) / (den0 * den0);
    dn2 = fmaxf(dn2, MINN);
    const float sc = cv * (cv * h - cu * paj) / den0;
    const float an = fmaxf(fabsf(cv) * sqrtf(nnj), MINN);
    const float numv = 2.f * sqrtc * sc;
    const float denv = fmaxf((1.f - c * dn2) * an, MINN);
    const float z = numv / denv;
    const float dist = asinhf(z) / sqrtc;
    dm[(I0 + ti) * NPT + (J0 + tj)] = expf(dist);
}

// ---------------- triplet scan: partials, NO atomics ----------------
__global__ __launch_bounds__(TTHR) void k_trip(const int* __restrict__ mask,
                                               const float* __restrict__ dm,
                                               double* __restrict__ psum,
                                               unsigned* __restrict__ pcnt) {
    __shared__ __align__(16) float dmrow[NPT];
    const int bx = blockIdx.x;
    const int i = bx >> 3;          // / CHUNKS
    const int chunk = bx & 7;       // % CHUNKS
    const int t = threadIdx.x;

    dmrow[t] = dm[i * NPT + t];     // TTHR == NPT: one element each
    __syncthreads();

    const int4* m4 = (const int4*)mask + (size_t)i * PLANE4 + (size_t)chunk * CHUNK4;
    const float4* dm4 = (const float4*)dmrow;
    const unsigned lin0 = (unsigned)(chunk * CHUNK4 + t);

    float s = 0.f;
    unsigned cnt = 0;

#define PROC(B, U) { \
        const unsigned lin = lin0 + TTHR * (U); \
        const unsigned jj = lin / 80u; \
        const unsigned k4 = lin - jj * 80u; \
        const float dij = dmrow[jj]; \
        const float4 dk = dm4[k4]; \
        const float t0 = dk.x - dij, t1 = dk.y - dij, t2 = dk.z - dij, t3 = dk.w - dij; \
        const bool p0 = (B).x && (t0 > 1e-16f); \
        const bool p1 = (B).y && (t1 > 1e-16f); \
        const bool p2 = (B).z && (t2 > 1e-16f); \
        const bool p3 = (B).w && (t3 > 1e-16f); \
        s += p0 ? t0 : 0.f; cnt += p0; \
        s += p1 ? t1 : 0.f; cnt += p1; \
        s += p2 ? t2 : 0.f; cnt += p2; \
        s += p3 ? t3 : 0.f; cnt += p3; }

    // 10 int4/thread: preload 8, consume 4 / load 2 / consume rest
    int4 b0 = m4[t + TTHR * 0], b1 = m4[t + TTHR * 1];
    int4 b2 = m4[t + TTHR * 2], b3 = m4[t + TTHR * 3];
    int4 b4 = m4[t + TTHR * 4], b5 = m4[t + TTHR * 5];
    int4 b6 = m4[t + TTHR * 6], b7 = m4[t + TTHR * 7];
    PROC(b0, 0) PROC(b1, 1) PROC(b2, 2) PROC(b3, 3)
    const int4 b8 = m4[t + TTHR * 8], b9 = m4[t + TTHR * 9];
    PROC(b4, 4) PROC(b5, 5) PROC(b6, 6) PROC(b7, 7)
    PROC(b8, 8) PROC(b9, 9)
#undef PROC

    // wave reduce (64 lanes), f64 from here on
    double sd = (double)s;
    for (int o = 32; o; o >>= 1) {
        sd += __shfl_down(sd, o);
        cnt += __shfl_down(cnt, o);
    }
    __shared__ double ss[5];
    __shared__ unsigned scn[5];
    const int w = t >> 6;
    if ((t & 63) == 0) { ss[w] = sd; scn[w] = cnt; }
    __syncthreads();
    if (t == 0) {
        psum[bx] = ss[0] + ss[1] + ss[2] + ss[3] + ss[4];
        pcnt[bx] = scn[0] + scn[1] + scn[2] + scn[3] + scn[4];
    }
}

// ---------------- final reduce of 2560 partials ----------------
__global__ __launch_bounds__(256) void k_fin(const double* __restrict__ psum,
                                             const unsigned* __restrict__ pcnt,
                                             float* __restrict__ out) {
    const int t = threadIdx.x;
    double s = 0.0;
    unsigned long long c = 0ULL;
    for (int v = t; v < NBLK; v += 256) {
        s += psum[v];
        c += (unsigned long long)pcnt[v];
    }
    for (int o = 32; o; o >>= 1) {
        s += __shfl_down(s, o);
        c += __shfl_down(c, o);
    }
    __shared__ double ss[4];
    __shared__ unsigned long long sc[4];
    const int w = t >> 6;
    if ((t & 63) == 0) { ss[w] = s; sc[w] = c; }
    __syncthreads();
    if (t == 0) {
        const double S = ss[0] + ss[1] + ss[2] + ss[3];
        unsigned long long C = sc[0] + sc[1] + sc[2] + sc[3];
        if (C == 0ULL) C = 1ULL;
        out[0] = (float)(S / (double)C);
    }
}

extern "C" void kernel_launch(void* const* d_in, const int* in_sizes, int n_in,
                              void* d_out, int out_size, void* d_ws, size_t ws_size,
                              hipStream_t stream) {
    const float* off  = (const float*)d_in[0];
    const float* nrm  = (const float*)d_in[1];
    const float* curv = (const float*)d_in[2];
    const int*   mask = (const int*)d_in[3];
    float* out = (float*)d_out;

    char* ws = (char*)d_ws;
    float* dm = (float*)(ws + 64);                           // 409600 B
    double* psum = (double*)(ws + 64 + 409600);              // 2560 * 8 B
    unsigned* pcnt = (unsigned*)(ws + 64 + 409600 + NBLK * 8); // 2560 * 4 B

    k_pre<<<dim3(NPT / 16, NPT / 16), 256, 0, stream>>>(off, nrm, curv, dm);
    k_trip<<<NBLK, TTHR, 0, stream>>>(mask, dm, psum, pcnt);
    k_fin<<<1, 256, 0, stream>>>(psum, pcnt, out);
}

// Round 7
// 37.883 us; speedup vs baseline: 1.7193x; 1.7193x over previous
//
#include <hip/hip_runtime.h>
#include <math.h>

#define NPT 320
#define DDIM 256
#define NN2 (NPT*NPT)          // 102400
#define MINN 1e-15f

#define CHUNKS 5
#define PLANE4 (NN2/4)         // 25600 int4 per plane
#define CHUNK4 (PLANE4/CHUNKS) // 5120 int4 per chunk
#define ITERS  (CHUNK4/256)    // 20 int4 per thread
#define NBLK   (NPT*CHUNKS)    // 1600 blocks

// ---------------- fused: row stats + dm tile ----------------
__global__ __launch_bounds__(256) void k_pre(const float* __restrict__ off,
                                             const float* __restrict__ nrm,
                                             const float* __restrict__ curv,
                                             float* __restrict__ dm) {
    __shared__ float sOI[16][260];
    __shared__ float sOJ[16][260];
    __shared__ float sNJ[16][260];
    __shared__ float sx2i[16], sx2j[16], snnj[16], spaj[16];
    const float c = curv[0];
    const float sqrtc = sqrtf(c);
    const int I0 = blockIdx.y * 16, J0 = blockIdx.x * 16;
    const int t = threadIdx.x;
    const int r = t >> 4;
    const int cc = t & 15;
    const int cb = cc << 4;     // 16 floats per thread

    const float4* pOI = (const float4*)&off[(I0 + r) * DDIM + cb];
    const float4* pOJ = (const float4*)&off[(J0 + r) * DDIM + cb];
    const float4* pNJ = (const float4*)&nrm[(J0 + r) * DDIM + cb];
#pragma unroll
    for (int q = 0; q < 4; ++q) {
        *(float4*)&sOI[r][cb + 4 * q] = pOI[q];
        *(float4*)&sOJ[r][cb + 4 * q] = pOJ[q];
        *(float4*)&sNJ[r][cb + 4 * q] = pNJ[q];
    }
    __syncthreads();

    // per-row stats computed in-tile: x2_i, x2_j, nn_j, pa_j
    float a0 = 0.f, a1 = 0.f, a2 = 0.f, a3 = 0.f;
#pragma unroll
    for (int q = 0; q < 16; ++q) {
        const float oi = sOI[r][cb + q];
        const float oj = sOJ[r][cb + q];
        const float nj = sNJ[r][cb + q];
        a0 = fmaf(oi, oi, a0);
        a1 = fmaf(oj, oj, a1);
        a2 = fmaf(nj, nj, a2);
        a3 = fmaf(oj, nj, a3);
    }
    for (int o = 1; o < 16; o <<= 1) {
        a0 += __shfl_xor(a0, o);
        a1 += __shfl_xor(a1, o);
        a2 += __shfl_xor(a2, o);
        a3 += __shfl_xor(a3, o);
    }
    if (cc == 0) { sx2i[r] = a0; sx2j[r] = a1; snnj[r] = a2; spaj[r] = a3; }
    __syncthreads();

    const int ti = t >> 4, tj = t & 15;
    float g = 0.f, h = 0.f;
#pragma unroll 8
    for (int d = 0; d < DDIM; ++d) {
        const float oi = sOI[ti][d];
        g = fmaf(oi, sOJ[tj][d], g);
        h = fmaf(oi, sNJ[tj][d], h);
    }

    const float x2i = sx2i[ti], x2j = sx2j[tj], nnj = snnj[tj], paj = spaj[tj];
    const float cu = 1.f - 2.f * c * g + c * x2i;
    const float cv = 1.f - c * x2j;
    float den0 = 1.f - 2.f * c * g + c * c * x2i * x2j;
    den0 = fmaxf(den0, MINN);
    float dn2 = (cu * cu * x2j - 2.f * cu * cv * g + cv * cv * x2i) / (den0 * den0);
    dn2 = fmaxf(dn2, MINN);
    const float sc = cv * (cv * h - cu * paj) / den0;
    const float an = fmaxf(fabsf(cv) * sqrtf(nnj), MINN);
    const float numv = 2.f * sqrtc * sc;
    const float denv = fmaxf((1.f - c * dn2) * an, MINN);
    const float z = numv / denv;
    const float dist = asinhf(z) / sqrtc;
    dm[(I0 + ti) * NPT + (J0 + tj)] = expf(dist);
}

// ---------------- triplet scan: partials, NO atomics ----------------
__global__ __launch_bounds__(256) void k_trip(const int* __restrict__ mask,
                                              const float* __restrict__ dm,
                                              double* __restrict__ psum,
                                              unsigned* __restrict__ pcnt) {
    __shared__ __align__(16) float dmrow[NPT];
    const int bx = blockIdx.x;
    const int i = bx / CHUNKS;
    const int chunk = bx - i * CHUNKS;
    const int t = threadIdx.x;

    for (int v = t; v < NPT; v += 256) dmrow[v] = dm[i * NPT + v];
    __syncthreads();

    const int4* m4 = (const int4*)mask + (size_t)i * PLANE4 + (size_t)chunk * CHUNK4;
    const float4* dm4 = (const float4*)dmrow;

    float s = 0.f;
    unsigned cnt = 0;

#define PROC(B, U) { \
        const unsigned lin = (unsigned)(chunk * CHUNK4 + t + 256 * (U)); \
        const unsigned jj = lin / 80u; \
        const unsigned k4 = lin - jj * 80u; \
        const float dij = dmrow[jj]; \
        const float4 dk = dm4[k4]; \
        const float t0 = dk.x - dij, t1 = dk.y - dij, t2 = dk.z - dij, t3 = dk.w - dij; \
        const bool p0 = (B).x && (t0 > 1e-16f); \
        const bool p1 = (B).y && (t1 > 1e-16f); \
        const bool p2 = (B).z && (t2 > 1e-16f); \
        const bool p3 = (B).w && (t3 > 1e-16f); \
        s += p0 ? t0 : 0.f; cnt += p0; \
        s += p1 ? t1 : 0.f; cnt += p1; \
        s += p2 ? t2 : 0.f; cnt += p2; \
        s += p3 ? t3 : 0.f; cnt += p3; }

#pragma unroll 1
    for (int g = 0; g < ITERS / 4; ++g) {
        const int u0 = g * 4;
        const int4 b0 = m4[t + 256 * (u0 + 0)];
        const int4 b1 = m4[t + 256 * (u0 + 1)];
        const int4 b2 = m4[t + 256 * (u0 + 2)];
        const int4 b3 = m4[t + 256 * (u0 + 3)];
        PROC(b0, u0 + 0)
        PROC(b1, u0 + 1)
        PROC(b2, u0 + 2)
        PROC(b3, u0 + 3)
    }
#undef PROC

    // wave reduce (64 lanes), f64 from here on
    double sd = (double)s;
    for (int o = 32; o; o >>= 1) {
        sd += __shfl_down(sd, o);
        cnt += __shfl_down(cnt, o);
    }
    __shared__ double ss[4];
    __shared__ unsigned scn[4];
    const int w = t >> 6;
    if ((t & 63) == 0) { ss[w] = sd; scn[w] = cnt; }
    __syncthreads();
    if (t == 0) {
        psum[bx] = ss[0] + ss[1] + ss[2] + ss[3];
        pcnt[bx] = scn[0] + scn[1] + scn[2] + scn[3];
    }
}

// ---------------- final reduce of 1600 partials ----------------
__global__ __launch_bounds__(256) void k_fin(const double* __restrict__ psum,
                                             const unsigned* __restrict__ pcnt,
                                             float* __restrict__ out) {
    const int t = threadIdx.x;
    double s = 0.0;
    unsigned long long c = 0ULL;
    for (int v = t; v < NBLK; v += 256) {
        s += psum[v];
        c += (unsigned long long)pcnt[v];
    }
    for (int o = 32; o; o >>= 1) {
        s += __shfl_down(s, o);
        c += __shfl_down(c, o);
    }
    __shared__ double ss[4];
    __shared__ unsigned long long sc[4];
    const int w = t >> 6;
    if ((t & 63) == 0) { ss[w] = s; sc[w] = c; }
    __syncthreads();
    if (t == 0) {
        const double S = ss[0] + ss[1] + ss[2] + ss[3];
        unsigned long long C = sc[0] + sc[1] + sc[2] + sc[3];
        if (C == 0ULL) C = 1ULL;
        out[0] = (float)(S / (double)C);
    }
}

extern "C" void kernel_launch(void* const* d_in, const int* in_sizes, int n_in,
                              void* d_out, int out_size, void* d_ws, size_t ws_size,
                              hipStream_t stream) {
    const float* off  = (const float*)d_in[0];
    const float* nrm  = (const float*)d_in[1];
    const float* curv = (const float*)d_in[2];
    const int*   mask = (const int*)d_in[3];
    float* out = (float*)d_out;

    char* ws = (char*)d_ws;
    float* dm = (float*)(ws + 64);                 // 409600 B
    double* psum = (double*)(ws + 64 + 409600);    // 1600 * 8 B
    unsigned* pcnt = (unsigned*)(ws + 64 + 409600 + NBLK * 8);  // 1600 * 4 B

    k_pre<<<dim3(NPT / 16, NPT / 16), 256, 0, stream>>>(off, nrm, curv, dm);
    k_trip<<<NBLK, 256, 0, stream>>>(mask, dm, psum, pcnt);
    k_fin<<<1, 256, 0, stream>>>(psum, pcnt, out);
}